// Round 16
// baseline (126.729 us; speedup 1.0000x reference)
//
#include <hip/hip_runtime.h>
#include <math.h>

#define NEG_BIG -9.0e15f

typedef __attribute__((ext_vector_type(4))) float f32x4;
typedef __attribute__((ext_vector_type(8))) short bf16x8;
typedef __attribute__((ext_vector_type(4))) unsigned int u32x4;

// H^T[o][i] = sum_k X[i][k] * W[k][o]   (X:[1024,128], W:[128,128], HT:[128,1024])
__global__ __launch_bounds__(128) void gemm_xw_t(const float* __restrict__ X,
                                                 const float* __restrict__ W,
                                                 float* __restrict__ HT) {
  __shared__ float xrow[128];
  const int i = blockIdx.x;
  const int o = threadIdx.x;
  xrow[o] = X[(size_t)i * 128 + o];
  __syncthreads();
  float acc = 0.f;
#pragma unroll 16
  for (int k = 0; k < 128; ++k) acc = fmaf(xrow[k], W[(size_t)k * 128 + o], acc);
  HT[(size_t)o * 1024 + i] = acc;
}

#define DOT4(acc, hv, p) \
  acc = fmaf(hv.x, p.x, fmaf(hv.y, p.y, fmaf(hv.z, p.z, fmaf(hv.w, p.w, acc))));

#define ABSFMA4R(accR, hv, hs, av)                  \
  accR.x = fmaf(fabsf(hv.x - hs), av, accR.x);      \
  accR.y = fmaf(fabsf(hv.y - hs), av, accR.y);      \
  accR.z = fmaf(fabsf(hv.z - hs), av, accR.z);      \
  accR.w = fmaf(fabsf(hv.w - hs), av, accR.w);

// Fused GAT layer v7: 2 rows/block, 512 blocks -> 2 blocks/CU (42 KB LDS,
// VGPR capped at 64 via launch_bounds(1024,8)). Same phase structure as the
// measured-best r9 kernel, halved row count for block-level latency overlap.
__global__ __launch_bounds__(1024, 8) void gat_attn(const float* __restrict__ HT,
                                                    const int* __restrict__ adj,
                                                    const float* __restrict__ a,
                                                    float* __restrict__ Xout) {
  __shared__ float4 ep4[4][2][256];   // 32 KB: [fq][row][jt]
  __shared__ float e_s[2][1024];      // 8 KB: p (post-softmax weights)
  __shared__ float2 h2_s[128];        // 1 KB: h_i[f] for the 2 rows
  __shared__ float a_s[128];
  __shared__ float redm[2][8];
  __shared__ float redsum[2][8];
  __shared__ float inv_s[2];

  const int t = threadIdx.x;
  const int i0 = blockIdx.x * 2;
  const float4* __restrict__ HT4 = reinterpret_cast<const float4*>(HT);

  if (t < 128) {
    h2_s[t] = *reinterpret_cast<const float2*>(HT + ((size_t)t << 10) + i0);
    a_s[t] = a[t];
  }
  __syncthreads();

  const int fq = t >> 8;        // 0..3 : f quarter
  const int jt = t & 255;       // float4 j-group

  // ---- phase 1: partials for 2 rows x 4 j over this thread's 32 f ----
  float4 ac0 = {0.f, 0.f, 0.f, 0.f};
  float4 ac1 = {0.f, 0.f, 0.f, 0.f};
#pragma unroll 8
  for (int ff = 0; ff < 32; ++ff) {
    const int f = fq * 32 + ff;
    const float4 hv = HT4[f * 256 + jt];   // coalesced, unique (f,jt)
    const float2 h2 = h2_s[f];             // b64 broadcast
    const float av = a_s[f];               // b32 broadcast
    ABSFMA4R(ac0, hv, h2.x, av);
    ABSFMA4R(ac1, hv, h2.y, av);
  }
  ep4[fq][0][jt] = ac0;
  ep4[fq][1][jt] = ac1;
  __syncthreads();

  // ---- partial reduce: thread (row = t>>9, jh = t&511) sums 4 fq float2s ----
  const int row = t >> 9;       // 0..1 (wave-uniform)
  const int jh = t & 511;       // float2 index over j
  float2 esum;
  {
    const float2* p0 = reinterpret_cast<const float2*>(&ep4[0][row][0]);
    const float2* p1 = reinterpret_cast<const float2*>(&ep4[1][row][0]);
    const float2* p2 = reinterpret_cast<const float2*>(&ep4[2][row][0]);
    const float2* p3 = reinterpret_cast<const float2*>(&ep4[3][row][0]);
    const float2 s0 = p0[jh], s1 = p1[jh], s2 = p2[jh], s3 = p3[jh];
    esum.x = (s0.x + s1.x) + (s2.x + s3.x);
    esum.y = (s0.y + s1.y) + (s2.y + s3.y);
  }

  // ---- mask + relu ----
  float2 e;
  {
    const int2 ad = *reinterpret_cast<const int2*>(&adj[(size_t)(i0 + row) * 1024 + jh * 2]);
    e.x = ad.x > 0 ? fmaxf(esum.x, 0.f) : NEG_BIG;
    e.y = ad.y > 0 ? fmaxf(esum.y, 0.f) : NEG_BIG;
  }

  // ---- softmax over j (8 waves per row) ----
  const int wq = (t >> 6) & 7;
  float m = fmaxf(e.x, e.y);
#pragma unroll
  for (int off = 32; off > 0; off >>= 1) m = fmaxf(m, __shfl_xor(m, off));
  if ((t & 63) == 0) redm[row][wq] = m;
  __syncthreads();
  {
    const float4 m0 = *reinterpret_cast<const float4*>(&redm[row][0]);
    const float4 m1 = *reinterpret_cast<const float4*>(&redm[row][4]);
    m = fmaxf(fmaxf(fmaxf(m0.x, m0.y), fmaxf(m0.z, m0.w)),
              fmaxf(fmaxf(m1.x, m1.y), fmaxf(m1.z, m1.w)));
  }
  float2 p;
  p.x = __expf(e.x - m);
  p.y = __expf(e.y - m);
  *reinterpret_cast<float2*>(&e_s[row][jh * 2]) = p;
  float s = p.x + p.y;
#pragma unroll
  for (int off = 32; off > 0; off >>= 1) s += __shfl_xor(s, off);
  if ((t & 63) == 0) redsum[row][wq] = s;
  __syncthreads();
  if (t < 2) {
    const float4 s0 = *reinterpret_cast<const float4*>(&redsum[t][0]);
    const float4 s1 = *reinterpret_cast<const float4*>(&redsum[t][4]);
    inv_s[t] = 1.f / (s0.x + s0.y + s0.z + s0.w + s1.x + s1.y + s1.z + s1.w);
  }
  __syncthreads();

  // ---- phase 3: out[r][f] = relu(inv[r] * sum_j p[r][j] * HT[f][j]) ----
  const int w = t >> 6;
  const int l = t & 63;
  const int f0 = w * 8;
  float acc[8][2];
#pragma unroll
  for (int ff = 0; ff < 8; ++ff) {
    acc[ff][0] = 0.f;
    acc[ff][1] = 0.f;
  }

#pragma unroll
  for (int jb = 0; jb < 4; ++jb) {
    const int j4 = jb * 64 + l;
    const float4 p0 = *reinterpret_cast<const float4*>(&e_s[0][j4 * 4]);
    const float4 p1 = *reinterpret_cast<const float4*>(&e_s[1][j4 * 4]);
#pragma unroll
    for (int ff = 0; ff < 8; ++ff) {
      const float4 hv = HT4[(f0 + ff) * 256 + j4];
      DOT4(acc[ff][0], hv, p0);
      DOT4(acc[ff][1], hv, p1);
    }
  }

  // merge-tree: 16 outputs across 64 lanes
  float v[16];
#pragma unroll
  for (int ff = 0; ff < 8; ++ff) {
    v[ff * 2 + 0] = acc[ff][0];
    v[ff * 2 + 1] = acc[ff][1];
  }
#pragma unroll
  for (int step = 0; step < 4; ++step) {
    const int s2 = 1 << step;
    const bool hi = (l & s2) != 0;
#pragma unroll
    for (int k = 0; k < (16 >> (step + 1)); ++k) {
      const float x = v[2 * k];
      const float y = v[2 * k + 1];
      float tt = hi ? x : y;
      tt = __shfl_xor(tt, s2);
      v[k] = (hi ? y : x) + tt;
    }
  }
  float r0 = v[0];
  r0 += __shfl_xor(r0, 16);
  r0 += __shfl_xor(r0, 32);

  if (l < 16) {
    const int ff = l >> 1;
    const int orow = l & 1;
    Xout[(size_t)(i0 + orow) * 128 + f0 + ff] = fmaxf(r0 * inv_s[orow], 0.f);
  }
}

// EdgeGCN head via bf16-split MFMA, 1024 blocks (one 32x32-pair tile each),
// 256 threads / 4 waves. (round-14 version -- UNCHANGED)
__global__ __launch_bounds__(256) void edge_fc_mfma(const float* __restrict__ X,
                                                    const float* __restrict__ Wfc,
                                                    const float* __restrict__ bfc,
                                                    float* __restrict__ out) {
  __shared__ float xi_s[32][132];
  __shared__ float xj_s[32][132];

  const int t = threadIdx.x;
  const int ib = blockIdx.x >> 5;
  const int jb = blockIdx.x & 31;

  {
    const int r = t >> 3;
    const int c0 = (t & 7) * 16;
    const float4* gi = reinterpret_cast<const float4*>(X + (size_t)(ib * 32 + r) * 128 + c0);
    const float4* gj = reinterpret_cast<const float4*>(X + (size_t)(jb * 32 + r) * 128 + c0);
#pragma unroll
    for (int k = 0; k < 4; ++k) {
      *reinterpret_cast<float4*>(&xi_s[r][c0 + k * 4]) = gi[k];
      *reinterpret_cast<float4*>(&xj_s[r][c0 + k * 4]) = gj[k];
    }
  }

  const int w = t >> 6, lane = t & 63;
  const int col = lane & 15, kg = lane >> 4;

  bf16x8 bhi[4], blo[4];
#pragma unroll
  for (int c = 0; c < 4; ++c) {
    bf16x8 bh, bl;
#pragma unroll
    for (int j = 0; j < 8; ++j) {
      const float wv = Wfc[(c * 32 + kg * 8 + j) * 16 + col];
      const unsigned u = __builtin_bit_cast(unsigned, wv);
      const unsigned h = u & 0xffff0000u;
      const float lof = wv - __builtin_bit_cast(float, h);
      bh[j] = (short)(h >> 16);
      bl[j] = (short)(__builtin_bit_cast(unsigned, lof) >> 16);
    }
    bhi[c] = bh;
    blo[c] = bl;
  }
  const float bb = bfc[col];

  __syncthreads();

  unsigned xjr[2][4][8];
#pragma unroll
  for (int jt = 0; jt < 2; ++jt) {
#pragma unroll
    for (int c = 0; c < 4; ++c) {
      const float4 v0 = *reinterpret_cast<const float4*>(&xj_s[jt * 16 + col][c * 32 + kg * 8]);
      const float4 v1 = *reinterpret_cast<const float4*>(&xj_s[jt * 16 + col][c * 32 + kg * 8 + 4]);
      xjr[jt][c][0] = __builtin_bit_cast(unsigned, v0.x);
      xjr[jt][c][1] = __builtin_bit_cast(unsigned, v0.y);
      xjr[jt][c][2] = __builtin_bit_cast(unsigned, v0.z);
      xjr[jt][c][3] = __builtin_bit_cast(unsigned, v0.w);
      xjr[jt][c][4] = __builtin_bit_cast(unsigned, v1.x);
      xjr[jt][c][5] = __builtin_bit_cast(unsigned, v1.y);
      xjr[jt][c][6] = __builtin_bit_cast(unsigned, v1.z);
      xjr[jt][c][7] = __builtin_bit_cast(unsigned, v1.w);
    }
  }

  const int iq = w;

  for (int i = 0; i < 8; ++i) {
    const int li = iq * 8 + i;
    const int gi = ib * 32 + li;
    f32x4 acc0 = {bb, bb, bb, bb};
    f32x4 acc1 = {bb, bb, bb, bb};
#pragma unroll
    for (int c = 0; c < 4; ++c) {
      const float4 v0 = *reinterpret_cast<const float4*>(&xi_s[li][c * 32 + kg * 8]);
      const float4 v1 = *reinterpret_cast<const float4*>(&xi_s[li][c * 32 + kg * 8 + 4]);
      unsigned xiv[8];
      xiv[0] = __builtin_bit_cast(unsigned, v0.x);
      xiv[1] = __builtin_bit_cast(unsigned, v0.y);
      xiv[2] = __builtin_bit_cast(unsigned, v0.z);
      xiv[3] = __builtin_bit_cast(unsigned, v0.w);
      xiv[4] = __builtin_bit_cast(unsigned, v1.x);
      xiv[5] = __builtin_bit_cast(unsigned, v1.y);
      xiv[6] = __builtin_bit_cast(unsigned, v1.z);
      xiv[7] = __builtin_bit_cast(unsigned, v1.w);
#pragma unroll
      for (int jt = 0; jt < 2; ++jt) {
        u32x4 ahv, alv;
#pragma unroll
        for (int q = 0; q < 4; ++q) {
          const float d0 = __builtin_bit_cast(float, xjr[jt][c][2 * q]) -
                           __builtin_bit_cast(float, xiv[2 * q]);
          const float d1 = __builtin_bit_cast(float, xjr[jt][c][2 * q + 1]) -
                           __builtin_bit_cast(float, xiv[2 * q + 1]);
          const unsigned h0 = __builtin_bit_cast(unsigned, d0) & 0x7fff0000u;
          const unsigned h1 = __builtin_bit_cast(unsigned, d1) & 0x7fff0000u;
          const float lo0 = fabsf(d0) - __builtin_bit_cast(float, h0);
          const float lo1 = fabsf(d1) - __builtin_bit_cast(float, h1);
          ahv[q] = __builtin_amdgcn_perm(h1, h0, 0x07060302u);
          alv[q] = __builtin_amdgcn_perm(__builtin_bit_cast(unsigned, lo1),
                                         __builtin_bit_cast(unsigned, lo0), 0x07060302u);
        }
        const bf16x8 ah = __builtin_bit_cast(bf16x8, ahv);
        const bf16x8 al = __builtin_bit_cast(bf16x8, alv);
        if (jt == 0) {
          acc0 = __builtin_amdgcn_mfma_f32_16x16x32_bf16(ah, bhi[c], acc0, 0, 0, 0);
          acc0 = __builtin_amdgcn_mfma_f32_16x16x32_bf16(ah, blo[c], acc0, 0, 0, 0);
          acc0 = __builtin_amdgcn_mfma_f32_16x16x32_bf16(al, bhi[c], acc0, 0, 0, 0);
        } else {
          acc1 = __builtin_amdgcn_mfma_f32_16x16x32_bf16(ah, bhi[c], acc1, 0, 0, 0);
          acc1 = __builtin_amdgcn_mfma_f32_16x16x32_bf16(ah, blo[c], acc1, 0, 0, 0);
          acc1 = __builtin_amdgcn_mfma_f32_16x16x32_bf16(al, bhi[c], acc1, 0, 0, 0);
        }
      }
    }
    const size_t obase = (size_t)gi * 1024;
#pragma unroll
    for (int r = 0; r < 4; ++r) {
      const int gj0 = jb * 32 + kg * 4 + r;
      const int gj1 = gj0 + 16;
      __builtin_nontemporal_store(acc0[r], out + (obase + gj0) * 16 + col);
      __builtin_nontemporal_store(acc1[r], out + (obase + gj1) * 16 + col);
    }
  }
}

extern "C" void kernel_launch(void* const* d_in, const int* in_sizes, int n_in,
                              void* d_out, int out_size, void* d_ws, size_t ws_size,
                              hipStream_t stream) {
  const float* feat = (const float*)d_in[0];
  const int* adj = (const int*)d_in[1];
  const float* W1 = (const float*)d_in[2];
  const float* a1 = (const float*)d_in[3];
  const float* W2 = (const float*)d_in[4];
  const float* a2 = (const float*)d_in[5];
  const float* W3 = (const float*)d_in[6];
  const float* a3 = (const float*)d_in[7];
  const float* Wfc = (const float*)d_in[8];
  const float* bfc = (const float*)d_in[9];
  float* out = (float*)d_out;

  float* ht = (float*)d_ws;        // 1024*128 (transposed H)
  float* xA = ht + 131072;         // 1024*128
  float* xB = xA + 131072;         // 1024*128

  gemm_xw_t<<<1024, 128, 0, stream>>>(feat, W1, ht);
  gat_attn<<<512, 1024, 0, stream>>>(ht, adj, a1, xA);
  gemm_xw_t<<<1024, 128, 0, stream>>>(xA, W2, ht);
  gat_attn<<<512, 1024, 0, stream>>>(ht, adj, a2, xB);
  gemm_xw_t<<<1024, 128, 0, stream>>>(xB, W3, ht);
  gat_attn<<<512, 1024, 0, stream>>>(ht, adj, a3, xA);
  edge_fc_mfma<<<1024, 256, 0, stream>>>(xA, Wfc, bfc, out);
}